// Round 3
// baseline (1373.854 us; speedup 1.0000x reference)
//
#include <hip/hip_runtime.h>

// AttentionRNN: B=64, NUM=8, TC=64, H=128. bn=512 sequences.
// 256 blocks x 512 threads (8 waves, 2/SIMD), 2 seqs/block, 64-step scan.
// GRU weights streamed from L2 every step (393KB/block/step), software-
// pipelined: 3 half-columns/thread, double-buffered 8-row chunks.
// uproj + att_w slices in registers. 5 barriers/step.

#define OFF_U     0      // [64][64] att_u (prologue only)
#define OFF_XMRM  4096   // [mat][seq][384]
#define OFF_HST   5632   // [2][128]
#define OFF_HPART 5888   // [2][64]
#define OFF_XTV   6016   // [2][128]
#define OFF_VV    6272   // [64]
#define OFF_RED   6336   // [8]
#define LDS_FLOATS 6352  // ~25 KB

// load one 8-row chunk of the thread's 3 half-columns (24 L2 loads)
#define LOADW(BUF, cc) do { \
    _Pragma("unroll") \
    for (int r_ = 0; r_ < 8; ++r_) { \
        BUF[r_]      = wb0[((cc)*8 + r_) * 384]; \
        BUF[8 + r_]  = wb1[((cc)*8 + r_) * 384]; \
        BUF[16 + r_] = wb2[((cc)*8 + r_) * 384]; \
    } \
} while (0)

// FMA one chunk: inputs are 2-address LDS broadcasts (conflict-free)
#define FMACHUNK(BUF, cc) do { \
    const int rb_ = halfBase + (cc)*8; \
    float4 xa0 = *(const float4*)(lds + OFF_XTV + rb_); \
    float4 xb0 = *(const float4*)(lds + OFF_XTV + rb_ + 4); \
    float4 xa1 = *(const float4*)(lds + OFF_XTV + 128 + rb_); \
    float4 xb1 = *(const float4*)(lds + OFF_XTV + 128 + rb_ + 4); \
    float4 sa0 = *(const float4*)(sel1 + rb_); \
    float4 sb0 = *(const float4*)(sel1 + rb_ + 4); \
    float4 sa1 = *(const float4*)(sel1 + 128 + rb_); \
    float4 sb1 = *(const float4*)(sel1 + 128 + rb_ + 4); \
    float4 ha0 = *(const float4*)(lds + OFF_HST + rb_); \
    float4 hb0 = *(const float4*)(lds + OFF_HST + rb_ + 4); \
    float4 ha1 = *(const float4*)(lds + OFF_HST + 128 + rb_); \
    float4 hb1 = *(const float4*)(lds + OFF_HST + 128 + rb_ + 4); \
    float x0_[8] = {xa0.x,xa0.y,xa0.z,xa0.w, xb0.x,xb0.y,xb0.z,xb0.w}; \
    float x1_[8] = {xa1.x,xa1.y,xa1.z,xa1.w, xb1.x,xb1.y,xb1.z,xb1.w}; \
    float s0_[8] = {sa0.x,sa0.y,sa0.z,sa0.w, sb0.x,sb0.y,sb0.z,sb0.w}; \
    float s1_[8] = {sa1.x,sa1.y,sa1.z,sa1.w, sb1.x,sb1.y,sb1.z,sb1.w}; \
    float h0_[8] = {ha0.x,ha0.y,ha0.z,ha0.w, hb0.x,hb0.y,hb0.z,hb0.w}; \
    float h1_[8] = {ha1.x,ha1.y,ha1.z,ha1.w, hb1.x,hb1.y,hb1.z,hb1.w}; \
    _Pragma("unroll") \
    for (int r_ = 0; r_ < 8; ++r_) { \
        a00 += BUF[r_]      * x0_[r_];  a01 += BUF[r_]      * x1_[r_]; \
        a10 += BUF[8 + r_]  * s0_[r_];  a11 += BUF[8 + r_]  * s1_[r_]; \
        a20 += BUF[16 + r_] * h0_[r_];  a21 += BUF[16 + r_] * h1_[r_]; \
    } \
} while (0)

__global__ __launch_bounds__(512)
void attn_gru_kernel(const float* __restrict__ x, const float* __restrict__ att_v,
                     const float* __restrict__ att_w, const float* __restrict__ att_u,
                     const float* __restrict__ gk, const float* __restrict__ grk,
                     const float* __restrict__ gbias, float* __restrict__ out) {
    __shared__ float lds[LDS_FLOATS];
    const int tid = threadIdx.x;
    const int bn0 = blockIdx.x * 2;

    for (int i = tid; i < 4096; i += 512) lds[OFF_U + i] = att_u[i];
    if (tid < 64) lds[OFF_VV + tid] = att_v[tid];
    if (tid < 256) lds[OFF_HST + tid] = 0.0f;
    __syncthreads();

    // thread mappings (all decompositions of the same tid)
    const int cseq = tid >> 8;            // seq for phases A/C
    const int chh  = (tid >> 1) & 127;    // feature (C)
    const int csh  = tid & 1;             // s-half (C)
    const int as   = (tid >> 2) & 63;     // s (A)
    const int aq   = tid & 3;             // h-quarter (A) — low bits -> shfl reduce
    const int half = tid & 1;             // row-half (D)
    const int c0   = tid >> 1;            // 0..255 (D)
    const int halfBase = half * 64;

    // ---- prologue: uproj half in registers
    float up[32];
    #pragma unroll
    for (int k = 0; k < 32; ++k) up[k] = 0.0f;
    {
        const float* xb = x + (size_t)(bn0 + cseq) * 8192 + chh;
        for (int t = 0; t < 64; ++t) {
            float xvp = xb[t * 128];
            const float4* Ur = (const float4*)(lds + OFF_U + t * 64 + csh * 32);
            #pragma unroll
            for (int k4 = 0; k4 < 8; ++k4) {
                float4 u = Ur[k4];
                up[k4*4+0] += xvp * u.x; up[k4*4+1] += xvp * u.y;
                up[k4*4+2] += xvp * u.z; up[k4*4+3] += xvp * u.w;
            }
        }
    }
    float sv = 0.0f;
    #pragma unroll
    for (int k = 0; k < 32; ++k) sv += lds[OFF_VV + csh * 32 + k];

    // att_w fragment: thread (cseq,as,aq) owns W[aq*32+k][as]
    float wreg[32];
    #pragma unroll
    for (int k = 0; k < 32; ++k) wreg[k] = att_w[(aq * 32 + k) * 64 + as];

    // ---- phase-D setup: 3 half-columns per thread (col768 = c0 + 256*i)
    const float* wb0 = gk + (size_t)halfBase * 384 + c0;               // i=0: always gk
    const int col1 = 256 + c0;
    const int m1   = (col1 >= 384) ? 1 : 0;                            // wave-uniform
    const int c1   = col1 - (m1 ? 384 : 0);
    const float* wb1 = (m1 ? grk : gk) + (size_t)halfBase * 384 + c1;
    const float* wb2 = grk + (size_t)halfBase * 384 + (128 + c0);      // i=2: always grk
    const float* sel1 = m1 ? (lds + OFF_HST) : (lds + OFF_XTV);
    const float b0 = gbias[c0];
    const float b1 = gbias[m1 * 384 + c1];
    const float b2 = gbias[384 + 128 + c0];
    const int o0 = c0;
    const int o1 = m1 * 768 + c1;
    const int o2 = 768 + 128 + c0;

    __syncthreads();

    float wA[24], wB[24];
    LOADW(wA, 0);   // chunk-0 in flight across A..C of step 0

    const float* xcol = x + (size_t)(bn0 + cseq) * 8192 + chh;

    #pragma unroll 1
    for (int t = 0; t < 64; ++t) {
        float xv = xcol[t * 128];   // L3-hot, hides under A

        // ---- A: h_part[s] partials, shfl-reduced over h-quarters
        {
            float pa = 0.0f;
            const float4* hb4 = (const float4*)(lds + OFF_HST + cseq * 128 + aq * 32);
            #pragma unroll
            for (int k4 = 0; k4 < 8; ++k4) {
                float4 hv = hb4[k4];
                pa += hv.x * wreg[k4*4+0] + hv.y * wreg[k4*4+1]
                    + hv.z * wreg[k4*4+2] + hv.w * wreg[k4*4+3];
            }
            pa += __shfl_xor(pa, 1);
            pa += __shfl_xor(pa, 2);
            if (aq == 0) lds[OFF_HPART + cseq * 64 + as] = pa;
        }
        __syncthreads();

        // ---- C: e = sum_s tanh(hp+up)*v  (s-half per lane), softmax (no max pass)
        float den = 0.0f;
        {
            const float4* hp4 = (const float4*)(lds + OFF_HPART + cseq * 64 + csh * 32);
            const float4* vv4 = (const float4*)(lds + OFF_VV + csh * 32);
            #pragma unroll
            for (int k4 = 0; k4 < 8; ++k4) {
                float4 hp = hp4[k4];
                float4 v4 = vv4[k4];
                den += v4.x * __fdividef(1.0f, __expf(2.0f * (hp.x + up[k4*4+0])) + 1.0f);
                den += v4.y * __fdividef(1.0f, __expf(2.0f * (hp.y + up[k4*4+1])) + 1.0f);
                den += v4.z * __fdividef(1.0f, __expf(2.0f * (hp.z + up[k4*4+2])) + 1.0f);
                den += v4.w * __fdividef(1.0f, __expf(2.0f * (hp.w + up[k4*4+3])) + 1.0f);
            }
        }
        float ep = sv - 2.0f * den;
        float e  = ep + __shfl_xor(ep, 1);          // pair lanes now both hold full e
        float p  = __expf(e);                       // |e| <= sum|v| ~ 5 : safe
        float wsum = p;
        #pragma unroll
        for (int off = 1; off <= 32; off <<= 1) wsum += __shfl_xor(wsum, off);
        if ((tid & 63) == 0) lds[OFF_RED + (tid >> 6)] = wsum;  // each hh counted twice
        __syncthreads();
        float denom = 0.5f * (lds[OFF_RED + cseq * 4 + 0] + lds[OFF_RED + cseq * 4 + 1]
                            + lds[OFF_RED + cseq * 4 + 2] + lds[OFF_RED + cseq * 4 + 3]);
        float av = __fdividef(p, denom);
        lds[OFF_XTV + cseq * 128 + chh] = av * xv;  // pair lanes write same value
        __syncthreads();

        // ---- D: xm/rm, double-buffered pipelined weight stream
        float a00 = 0.f, a01 = 0.f, a10 = 0.f, a11 = 0.f, a20 = 0.f, a21 = 0.f;
        LOADW(wB, 1); FMACHUNK(wA, 0);
        LOADW(wA, 2); FMACHUNK(wB, 1);
        LOADW(wB, 3); FMACHUNK(wA, 2);
        LOADW(wA, 4); FMACHUNK(wB, 3);
        LOADW(wB, 5); FMACHUNK(wA, 4);
        LOADW(wA, 6); FMACHUNK(wB, 5);
        LOADW(wB, 7); FMACHUNK(wA, 6);
        FMACHUNK(wB, 7);
        a00 += __shfl_xor(a00, 1); a01 += __shfl_xor(a01, 1);
        a10 += __shfl_xor(a10, 1); a11 += __shfl_xor(a11, 1);
        a20 += __shfl_xor(a20, 1); a21 += __shfl_xor(a21, 1);
        if (half == 0) {
            lds[OFF_XMRM + o0]       = a00 + b0;
            lds[OFF_XMRM + o0 + 384] = a01 + b0;
            lds[OFF_XMRM + o1]       = a10 + b1;
            lds[OFF_XMRM + o1 + 384] = a11 + b1;
            lds[OFF_XMRM + o2]       = a20 + b2;
            lds[OFF_XMRM + o2 + 384] = a21 + b2;
        }
        __syncthreads();

        LOADW(wA, 0);   // next step's chunk 0: lands under E + barrier + A + C

        // ---- E: gates + h update
        if (tid < 256) {
            const int eseq = tid >> 7, ehh = tid & 127;
            const float* xm = lds + OFF_XMRM + eseq * 384;
            const float* rm = lds + OFF_XMRM + 768 + eseq * 384;
            float xz = xm[ehh], xr = xm[128 + ehh], xh = xm[256 + ehh];
            float rz = rm[ehh], rr = rm[128 + ehh], rh = rm[256 + ehh];
            float z = __fdividef(1.0f, 1.0f + __expf(-(xz + rz)));
            float r = __fdividef(1.0f, 1.0f + __expf(-(xr + rr)));
            float hc = xh + r * rh;
            hc = hc > 0.0f ? hc : 0.0f;
            float hold = lds[OFF_HST + eseq * 128 + ehh];
            lds[OFF_HST + eseq * 128 + ehh] = z * hold + (1.0f - z) * hc;
        }
        __syncthreads();
    }

    if (tid < 256) {
        const int eseq = tid >> 7, ehh = tid & 127;
        out[(size_t)(bn0 + eseq) * 128 + ehh] = lds[OFF_HST + eseq * 128 + ehh];
    }
}

extern "C" void kernel_launch(void* const* d_in, const int* in_sizes, int n_in,
                              void* d_out, int out_size, void* d_ws, size_t ws_size,
                              hipStream_t stream) {
    (void)in_sizes; (void)n_in; (void)out_size; (void)d_ws; (void)ws_size;
    const float* x      = (const float*)d_in[0];
    const float* att_v  = (const float*)d_in[1];
    const float* att_w  = (const float*)d_in[2];
    const float* att_u  = (const float*)d_in[3];
    const float* gk     = (const float*)d_in[4];
    const float* grk    = (const float*)d_in[5];
    const float* gbias  = (const float*)d_in[6];
    float* out = (float*)d_out;
    hipLaunchKernelGGL(attn_gru_kernel, dim3(256), dim3(512), 0, stream,
                       x, att_v, att_w, att_u, gk, grk, gbias, out);
}

// Round 5
// 1141.822 us; speedup vs baseline: 1.2032x; 1.2032x over previous
//
#include <hip/hip_runtime.h>

// AttentionRNN: B=64, NUM=8, TC=64, H=128. bn=512 sequences.
// 256 blocks x 512 threads, 2 seqs/block, 64-step scan. 1 block/CU forced by
// 86KB LDS (-> VGPR budget 256, no spill). GRU weights streamed from L2 as
// float4 col-quads (384 D-threads), inputs via wave-uniform LDS broadcast,
// halves combined in phase E.
// R5 fix: bias staging was short by 512 entries (uninit LDS read in E).

#define OFF_U      0       // [64][64] att_u
#define OFF_PART   4096    // [half(2)][seq(2)][768] phase-D partials
#define OFF_HST    7168    // [2][128] h state
#define OFF_HPART  7424    // [2][64]
#define OFF_XTV    7552    // [2][128] x_t = a*x_col
#define OFF_VV     7808    // [64]
#define OFF_BIAS   7872    // [2][384]
#define OFF_RED    8640    // [8]
#define LDS_FLOATS 22016   // 86 KB: forces 1 block/CU (2x86KB > 160KB)

#define FMA4(ACC, W, S) do { (ACC).x += (W).x*(S); (ACC).y += (W).y*(S); \
                             (ACC).z += (W).z*(S); (ACC).w += (W).w*(S); } while(0)

#define DLOADW(BUF, cc) do { \
    _Pragma("unroll") \
    for (int r_ = 0; r_ < 8; ++r_) BUF[r_] = *(const float4*)(Wq + (size_t)((cc)*8 + r_)*384); \
} while(0)

#define DFMA(BUF, cc) do { \
    const int rb_ = dhalf*64 + (cc)*8; \
    _Pragma("unroll") \
    for (int r4_ = 0; r4_ < 2; ++r4_) { \
        float4 i0_ = *(const float4*)(lds + din + rb_ + r4_*4); \
        float4 i1_ = *(const float4*)(lds + din + 128 + rb_ + r4_*4); \
        FMA4(acc0, BUF[r4_*4+0], i0_.x); FMA4(acc1, BUF[r4_*4+0], i1_.x); \
        FMA4(acc0, BUF[r4_*4+1], i0_.y); FMA4(acc1, BUF[r4_*4+1], i1_.y); \
        FMA4(acc0, BUF[r4_*4+2], i0_.z); FMA4(acc1, BUF[r4_*4+2], i1_.z); \
        FMA4(acc0, BUF[r4_*4+3], i0_.w); FMA4(acc1, BUF[r4_*4+3], i1_.w); \
    } \
} while(0)

__global__ void __launch_bounds__(512) __attribute__((amdgpu_waves_per_eu(2, 2)))
attn_gru_kernel(const float* __restrict__ x, const float* __restrict__ att_v,
                const float* __restrict__ att_w, const float* __restrict__ att_u,
                const float* __restrict__ gk, const float* __restrict__ grk,
                const float* __restrict__ gbias, float* __restrict__ out) {
    __shared__ float lds[LDS_FLOATS];
    const int tid = threadIdx.x;
    const int bn0 = blockIdx.x * 2;

    // ---- stage U, v, bias; zero h
    for (int i = tid; i < 4096; i += 512) lds[OFF_U + i] = att_u[i];
    if (tid < 64)  lds[OFF_VV + tid] = att_v[tid];
    if (tid < 256) lds[OFF_HST + tid] = 0.0f;
    for (int i = tid; i < 768; i += 512) lds[OFF_BIAS + i] = gbias[i];   // R5 fix
    __syncthreads();

    // ---- thread mappings
    const int cseq = tid >> 8;            // phase C / softmax seq
    const int chh  = (tid >> 1) & 127;    // feature
    const int csh  = tid & 1;             // s-half
    const int as   = (tid >> 2) & 63;     // phase A: s
    const int aq   = tid & 3;             // phase A: h-quarter (adjacent lanes)
    // phase D: 384 active threads, quad of cols x half of rows
    const int dact  = (tid < 384);
    const int dhalf = (tid >= 192 && tid < 384) ? 1 : 0;
    const int q     = dact ? (tid - dhalf * 192) : 0;   // 0..191
    const int col4  = q * 4;                            // 0..764
    const int dmat  = (col4 >= 384) ? 1 : 0;            // 0: gk (x_t), 1: grk (h)
    const int dcol  = col4 - dmat * 384;
    const float* Wq = (dmat ? grk : gk) + (size_t)(dhalf * 64) * 384 + dcol;
    const int din   = dmat ? OFF_HST : OFF_XTV;

    // ---- prologue: uproj half in registers (32/thread)
    float up[32];
    #pragma unroll
    for (int k = 0; k < 32; ++k) up[k] = 0.0f;
    {
        const float* xb = x + (size_t)(bn0 + cseq) * 8192 + chh;
        for (int t = 0; t < 64; ++t) {
            float xvp = xb[t * 128];
            const float4* Ur = (const float4*)(lds + OFF_U + t * 64 + csh * 32);
            #pragma unroll
            for (int k4 = 0; k4 < 8; ++k4) {
                float4 u = Ur[k4];
                up[k4*4+0] += xvp * u.x; up[k4*4+1] += xvp * u.y;
                up[k4*4+2] += xvp * u.z; up[k4*4+3] += xvp * u.w;
            }
        }
    }
    float sv = 0.0f;
    #pragma unroll
    for (int k = 0; k < 32; ++k) sv += lds[OFF_VV + csh * 32 + k];

    // phase-A att_w fragment in registers
    float wreg[32];
    #pragma unroll
    for (int k = 0; k < 32; ++k) wreg[k] = att_w[(aq * 32 + k) * 64 + as];

    __syncthreads();

    const float* xcol = x + (size_t)(bn0 + cseq) * 8192 + chh;

    #pragma unroll 1
    for (int t = 0; t < 64; ++t) {
        float4 wA[8], wB[8];
        if (dact) DLOADW(wA, 0);        // prefetch: fetch overlaps phases A+C
        float xv = xcol[t * 128];

        // ---- A: h_part[s] partials over h-quarters, shfl-reduced
        {
            float pa = 0.0f;
            const float4* hb4 = (const float4*)(lds + OFF_HST + cseq * 128 + aq * 32);
            #pragma unroll
            for (int k4 = 0; k4 < 8; ++k4) {
                float4 hv = hb4[k4];
                pa += hv.x * wreg[k4*4+0] + hv.y * wreg[k4*4+1]
                    + hv.z * wreg[k4*4+2] + hv.w * wreg[k4*4+3];
            }
            pa += __shfl_xor(pa, 1);
            pa += __shfl_xor(pa, 2);
            if (aq == 0) lds[OFF_HPART + cseq * 64 + as] = pa;
        }
        __syncthreads();

        // ---- C: e = sum_s tanh(hp+up)*v (s-half per lane pair); max-free softmax
        float den = 0.0f;
        {
            const float4* hp4 = (const float4*)(lds + OFF_HPART + cseq * 64 + csh * 32);
            const float4* vv4 = (const float4*)(lds + OFF_VV + csh * 32);
            #pragma unroll
            for (int k4 = 0; k4 < 8; ++k4) {
                float4 hp = hp4[k4];
                float4 v4 = vv4[k4];
                den += v4.x * __fdividef(1.0f, __expf(2.0f * (hp.x + up[k4*4+0])) + 1.0f);
                den += v4.y * __fdividef(1.0f, __expf(2.0f * (hp.y + up[k4*4+1])) + 1.0f);
                den += v4.z * __fdividef(1.0f, __expf(2.0f * (hp.z + up[k4*4+2])) + 1.0f);
                den += v4.w * __fdividef(1.0f, __expf(2.0f * (hp.w + up[k4*4+3])) + 1.0f);
            }
        }
        float ep = sv - 2.0f * den;
        float e  = ep + __shfl_xor(ep, 1);      // both pair lanes hold full e
        float p  = __expf(e);                   // |e| <= sum|v| ~ 5: fp32-safe
        float wsum = p;
        #pragma unroll
        for (int off = 1; off <= 32; off <<= 1) wsum += __shfl_xor(wsum, off);
        if ((tid & 63) == 0) lds[OFF_RED + (tid >> 6)] = wsum;  // each hh counted 2x
        __syncthreads();
        float denom = 0.5f * (lds[OFF_RED + cseq * 4 + 0] + lds[OFF_RED + cseq * 4 + 1]
                            + lds[OFF_RED + cseq * 4 + 2] + lds[OFF_RED + cseq * 4 + 3]);
        float av = __fdividef(p, denom);
        lds[OFF_XTV + cseq * 128 + chh] = av * xv;   // pair lanes write same value
        __syncthreads();

        // ---- D: partial xm/rm. 384 threads, float4 weight stream, dbuf chunks.
        if (dact) {
            float4 acc0 = make_float4(0.f, 0.f, 0.f, 0.f);
            float4 acc1 = make_float4(0.f, 0.f, 0.f, 0.f);
            DLOADW(wB, 1); DFMA(wA, 0);
            DLOADW(wA, 2); DFMA(wB, 1);
            DLOADW(wB, 3); DFMA(wA, 2);
            DLOADW(wA, 4); DFMA(wB, 3);
            DLOADW(wB, 5); DFMA(wA, 4);
            DLOADW(wA, 6); DFMA(wB, 5);
            DLOADW(wB, 7); DFMA(wA, 6);
            DFMA(wB, 7);
            *(float4*)(lds + OFF_PART + (dhalf * 2 + 0) * 768 + col4) = acc0;
            *(float4*)(lds + OFF_PART + (dhalf * 2 + 1) * 768 + col4) = acc1;
        }
        __syncthreads();

        // ---- E: combine halves + bias, gates, h update
        if (tid < 256) {
            const int eseq = tid >> 7, ehh = tid & 127;
            const float* p0 = lds + OFF_PART + (0 * 2 + eseq) * 768;
            const float* p1 = lds + OFF_PART + (1 * 2 + eseq) * 768;
            const float* bs = lds + OFF_BIAS;
            float xz = p0[ehh]       + p1[ehh]       + bs[ehh];
            float xr = p0[128 + ehh] + p1[128 + ehh] + bs[128 + ehh];
            float xh = p0[256 + ehh] + p1[256 + ehh] + bs[256 + ehh];
            float rz = p0[384 + ehh] + p1[384 + ehh] + bs[384 + ehh];
            float rr = p0[512 + ehh] + p1[512 + ehh] + bs[512 + ehh];
            float rh = p0[640 + ehh] + p1[640 + ehh] + bs[640 + ehh];
            float z = __fdividef(1.0f, 1.0f + __expf(-(xz + rz)));
            float r = __fdividef(1.0f, 1.0f + __expf(-(xr + rr)));
            float hc = xh + r * rh;
            hc = hc > 0.0f ? hc : 0.0f;
            float hold = lds[OFF_HST + eseq * 128 + ehh];
            lds[OFF_HST + eseq * 128 + ehh] = z * hold + (1.0f - z) * hc;
        }
        __syncthreads();
    }

    if (tid < 256) {
        const int eseq = tid >> 7, ehh = tid & 127;
        out[(size_t)(bn0 + eseq) * 128 + ehh] = lds[OFF_HST + eseq * 128 + ehh];
    }
}

extern "C" void kernel_launch(void* const* d_in, const int* in_sizes, int n_in,
                              void* d_out, int out_size, void* d_ws, size_t ws_size,
                              hipStream_t stream) {
    (void)in_sizes; (void)n_in; (void)out_size; (void)d_ws; (void)ws_size;
    const float* x      = (const float*)d_in[0];
    const float* att_v  = (const float*)d_in[1];
    const float* att_w  = (const float*)d_in[2];
    const float* att_u  = (const float*)d_in[3];
    const float* gk     = (const float*)d_in[4];
    const float* grk    = (const float*)d_in[5];
    const float* gbias  = (const float*)d_in[6];
    float* out = (float*)d_out;
    hipLaunchKernelGGL(attn_gru_kernel, dim3(256), dim3(512), 0, stream,
                       x, att_v, att_w, att_u, gk, grk, gbias, out);
}

// Round 8
// 990.584 us; speedup vs baseline: 1.3869x; 1.1527x over previous
//
#include <hip/hip_runtime.h>

// AttentionRNN: B=64, NUM=8, TC=64, H=128. bn=512 sequences.
// 256 blocks x 512 threads, 2 seqs/block, 64-step scan, 1 block/CU (105KB LDS).
// R8: phase D streams fp32 GRU weights via global_load_lds into a 2-buffer
// 48KB-chunk pipeline synchronized ONLY by __syncthreads() (m97 semantics:
// barrier drains vmcnt -> all waves' DMA landed; compiler-visible, no asm).
// Chunk k+1 issued right after the barrier opening chunk k (1-deep overlap).
// A/C/E phases verbatim from validated R5.

#define CHUNK_FL  12288        // 16 rows x 384 cols x 2 mats (48KB)
#define OFF_WBUF  0            // [2][12288]; U aliased in wbuf[0][0..4095]
#define OFF_HST   24576        // [2][128]
#define OFF_HPARTX 24832       // [2][64]
#define OFF_XTV   24960        // [2][128]
#define OFF_XMRM  25216        // [2][2][384] (bias folded in)
#define OFF_VV    26752        // [64]
#define OFF_RED   26816        // [8]
#define LDS_FLOATS 26824       // ~104.8 KB -> 1 block/CU

#define FMA4(ACC, W, S) do { (ACC).x += (W).x*(S); (ACC).y += (W).y*(S); \
                             (ACC).z += (W).z*(S); (ACC).w += (W).w*(S); } while(0)

__device__ __forceinline__ void gld_lds16(const float* g, float* l) {
    __builtin_amdgcn_global_load_lds(
        (const __attribute__((address_space(1))) unsigned int*)g,
        (__attribute__((address_space(3))) unsigned int*)l, 16, 0, 0);
}

// issue one 48KB chunk (chunk index K, buffer BUF): 6 insts/wave x 8 waves
#define ISSUE(K, BUF) do { \
    _Pragma("unroll") \
    for (int i_ = 0; i_ < 6; ++i_) \
        gld_lds16(gq + (K)*6144 + i_*256, lq + (BUF)*CHUNK_FL + i_*256); \
} while (0)

__global__ void __launch_bounds__(512)
attn_gru_kernel(const float* __restrict__ x, const float* __restrict__ att_v,
                const float* __restrict__ att_w, const float* __restrict__ att_u,
                const float* __restrict__ gk, const float* __restrict__ grk,
                const float* __restrict__ gbias, float* __restrict__ out) {
    __shared__ float lds[LDS_FLOATS];
    const int tid = threadIdx.x;
    const int bn0 = blockIdx.x * 2;

    // ---- stage U (aliased into wbuf[0]), VV; zero h
    for (int i = tid; i < 4096; i += 512) lds[OFF_WBUF + i] = att_u[i];
    if (tid < 64)  lds[OFF_VV + tid] = att_v[tid];
    if (tid < 256) lds[OFF_HST + tid] = 0.0f;
    __syncthreads();

    // ---- thread mappings
    const int cseq = tid >> 8;            // phase A/C seq
    const int chh  = (tid >> 1) & 127;    // feature
    const int csh  = tid & 1;             // s-half
    const int as   = (tid >> 2) & 63;     // phase A: s
    const int aq   = tid & 3;             // phase A: h-quarter (adjacent lanes)
    // phase D FMA: 384 threads = mat x col-quad x row-half(adjacent lanes)
    const int dact = (tid < 384);
    const int dm   = (tid >= 192) ? 1 : 0;
    const int du   = tid - dm * 192;      // 0..191
    const int dcq  = du >> 1;             // 0..95 -> cols 4dcq..4dcq+3
    const int drh  = du & 1;              // row half (8 rows within chunk)
    const int din  = dm ? OFF_HST : OFF_XTV;
    const int dwoff = dm * 6144 + drh * 3072 + 4 * dcq;
    float4 bias4 = make_float4(0.f, 0.f, 0.f, 0.f);
    if (dact) bias4 = *(const float4*)(gbias + dm * 384 + 4 * dcq);
    // phase D copy lanes (all 8 waves): quarter of gk or grk per wave
    const int wv = tid >> 6, lane = tid & 63;
    const float* gq = ((wv < 4) ? gk : grk) + (wv & 3) * 1536 + lane * 4;
    float* lq = lds + OFF_WBUF + ((wv >= 4) ? 6144 : 0) + (wv & 3) * 1536 + lane * 4;

    // ---- prologue: uproj half in registers (32/thread), from U in lds
    float up[32];
    #pragma unroll
    for (int k = 0; k < 32; ++k) up[k] = 0.0f;
    {
        const float* xb = x + (size_t)(bn0 + cseq) * 8192 + chh;
        for (int t = 0; t < 64; ++t) {
            float xvp = xb[t * 128];
            const float4* Ur = (const float4*)(lds + OFF_WBUF + t * 64 + csh * 32);
            #pragma unroll
            for (int k4 = 0; k4 < 8; ++k4) {
                float4 u = Ur[k4];
                up[k4*4+0] += xvp * u.x; up[k4*4+1] += xvp * u.y;
                up[k4*4+2] += xvp * u.z; up[k4*4+3] += xvp * u.w;
            }
        }
    }
    float sv = 0.0f;
    #pragma unroll
    for (int k = 0; k < 32; ++k) sv += lds[OFF_VV + csh * 32 + k];

    __syncthreads();        // everyone done reading U before buf0 is overwritten
    ISSUE(0, 0);            // chunk 0 of step 0 in flight across phases A+C

    const float* xcol = x + (size_t)(bn0 + cseq) * 8192 + chh;

    #pragma unroll 1
    for (int t = 0; t < 64; ++t) {
        float xv = xcol[t * 128];

        // ---- A: h_part[s] partials over h-quarters, shfl-reduced (att_w from L2)
        {
            float pa = 0.0f;
            const float4* hb4 = (const float4*)(lds + OFF_HST + cseq * 128 + aq * 32);
            const float* wgl = att_w + aq * 32 * 64 + as;
            #pragma unroll
            for (int k4 = 0; k4 < 8; ++k4) {
                float4 hv = hb4[k4];
                pa += hv.x * wgl[(k4*4+0)*64] + hv.y * wgl[(k4*4+1)*64]
                    + hv.z * wgl[(k4*4+2)*64] + hv.w * wgl[(k4*4+3)*64];
            }
            pa += __shfl_xor(pa, 1);
            pa += __shfl_xor(pa, 2);
            if (aq == 0) lds[OFF_HPARTX + cseq * 64 + as] = pa;
        }
        __syncthreads();

        // ---- C: e = sum_s tanh(hp+up)*v (s-half per lane pair); max-free softmax
        float den = 0.0f;
        {
            const float4* hp4 = (const float4*)(lds + OFF_HPARTX + cseq * 64 + csh * 32);
            const float4* vv4 = (const float4*)(lds + OFF_VV + csh * 32);
            #pragma unroll
            for (int k4 = 0; k4 < 8; ++k4) {
                float4 hp = hp4[k4];
                float4 v4 = vv4[k4];
                den += v4.x * __fdividef(1.0f, __expf(2.0f * (hp.x + up[k4*4+0])) + 1.0f);
                den += v4.y * __fdividef(1.0f, __expf(2.0f * (hp.y + up[k4*4+1])) + 1.0f);
                den += v4.z * __fdividef(1.0f, __expf(2.0f * (hp.z + up[k4*4+2])) + 1.0f);
                den += v4.w * __fdividef(1.0f, __expf(2.0f * (hp.w + up[k4*4+3])) + 1.0f);
            }
        }
        float ep = sv - 2.0f * den;
        float e  = ep + __shfl_xor(ep, 1);      // both pair lanes hold full e
        float p  = __expf(e);                   // |e| <= sum|v| ~ 5: fp32-safe
        float wsum = p;
        #pragma unroll
        for (int off = 1; off <= 32; off <<= 1) wsum += __shfl_xor(wsum, off);
        if ((tid & 63) == 0) lds[OFF_RED + (tid >> 6)] = wsum;  // each hh counted 2x
        __syncthreads();
        float denom = 0.5f * (lds[OFF_RED + cseq * 4 + 0] + lds[OFF_RED + cseq * 4 + 1]
                            + lds[OFF_RED + cseq * 4 + 2] + lds[OFF_RED + cseq * 4 + 3]);
        float av = __fdividef(p, denom);
        lds[OFF_XTV + cseq * 128 + chh] = av * xv;   // pair lanes write same value
        __syncthreads();

        // ---- D: 8-chunk gld_lds pipeline, __syncthreads-synchronized (m97 style)
        float4 acc0 = make_float4(0.f, 0.f, 0.f, 0.f);
        float4 acc1 = make_float4(0.f, 0.f, 0.f, 0.f);
        #pragma unroll
        for (int k = 0; k < 8; ++k) {
            __syncthreads();   // drains vmcnt: chunk k landed (all waves);
                               // readers of buf[(k+1)&1] (chunk k-1) are done
            if (k < 7)       ISSUE(k + 1, (k + 1) & 1);
            else if (t < 63) ISSUE(0, 0);          // prefetch next step's chunk 0
            if (dact) {
                const float* wb = lds + OFF_WBUF + (k & 1) * CHUNK_FL + dwoff;
                float4 w0 = *(const float4*)(wb);
                float4 w1 = *(const float4*)(wb + 384);
                float4 w2 = *(const float4*)(wb + 768);
                float4 w3 = *(const float4*)(wb + 1152);
                float4 w4 = *(const float4*)(wb + 1536);
                float4 w5 = *(const float4*)(wb + 1920);
                float4 w6 = *(const float4*)(wb + 2304);
                float4 w7 = *(const float4*)(wb + 2688);
                const float* ibase = lds + din + k * 16 + drh * 8;
                float4 p0 = *(const float4*)(ibase);
                float4 p1 = *(const float4*)(ibase + 4);
                float4 q0 = *(const float4*)(ibase + 128);
                float4 q1 = *(const float4*)(ibase + 132);
                FMA4(acc0, w0, p0.x); FMA4(acc1, w0, q0.x);
                FMA4(acc0, w1, p0.y); FMA4(acc1, w1, q0.y);
                FMA4(acc0, w2, p0.z); FMA4(acc1, w2, q0.z);
                FMA4(acc0, w3, p0.w); FMA4(acc1, w3, q0.w);
                FMA4(acc0, w4, p1.x); FMA4(acc1, w4, q1.x);
                FMA4(acc0, w5, p1.y); FMA4(acc1, w5, q1.y);
                FMA4(acc0, w6, p1.z); FMA4(acc1, w6, q1.z);
                FMA4(acc0, w7, p1.w); FMA4(acc1, w7, q1.w);
            }
        }

        // combine row-halves (adjacent lanes) and store complete dots + bias
        if (dact) {
            acc0.x += __shfl_xor(acc0.x, 1); acc0.y += __shfl_xor(acc0.y, 1);
            acc0.z += __shfl_xor(acc0.z, 1); acc0.w += __shfl_xor(acc0.w, 1);
            acc1.x += __shfl_xor(acc1.x, 1); acc1.y += __shfl_xor(acc1.y, 1);
            acc1.z += __shfl_xor(acc1.z, 1); acc1.w += __shfl_xor(acc1.w, 1);
            if (drh == 0) {
                *(float4*)(lds + OFF_XMRM + (dm * 2 + 0) * 384 + 4 * dcq) =
                    make_float4(acc0.x + bias4.x, acc0.y + bias4.y,
                                acc0.z + bias4.z, acc0.w + bias4.w);
                *(float4*)(lds + OFF_XMRM + (dm * 2 + 1) * 384 + 4 * dcq) =
                    make_float4(acc1.x + bias4.x, acc1.y + bias4.y,
                                acc1.z + bias4.z, acc1.w + bias4.w);
            }
        }
        __syncthreads();

        // ---- E: gates + h update (bias already in XMRM)
        if (tid < 256) {
            const int eseq = tid >> 7, ehh = tid & 127;
            const float* xm = lds + OFF_XMRM + (0 * 2 + eseq) * 384;
            const float* rm = lds + OFF_XMRM + (1 * 2 + eseq) * 384;
            float xz = xm[ehh], xr = xm[128 + ehh], xh_ = xm[256 + ehh];
            float rz = rm[ehh], rr = rm[128 + ehh], rh = rm[256 + ehh];
            float z = __fdividef(1.0f, 1.0f + __expf(-(xz + rz)));
            float r = __fdividef(1.0f, 1.0f + __expf(-(xr + rr)));
            float hc = xh_ + r * rh;
            hc = hc > 0.0f ? hc : 0.0f;
            float hold = lds[OFF_HST + eseq * 128 + ehh];
            lds[OFF_HST + eseq * 128 + ehh] = z * hold + (1.0f - z) * hc;
        }
        __syncthreads();
    }

    if (tid < 256) {
        const int eseq = tid >> 7, ehh = tid & 127;
        out[(size_t)(bn0 + eseq) * 128 + ehh] = lds[OFF_HST + eseq * 128 + ehh];
    }
}

extern "C" void kernel_launch(void* const* d_in, const int* in_sizes, int n_in,
                              void* d_out, int out_size, void* d_ws, size_t ws_size,
                              hipStream_t stream) {
    (void)in_sizes; (void)n_in; (void)out_size; (void)d_ws; (void)ws_size;
    const float* x      = (const float*)d_in[0];
    const float* att_v  = (const float*)d_in[1];
    const float* att_w  = (const float*)d_in[2];
    const float* att_u  = (const float*)d_in[3];
    const float* gk     = (const float*)d_in[4];
    const float* grk    = (const float*)d_in[5];
    const float* gbias  = (const float*)d_in[6];
    float* out = (float*)d_out;
    hipLaunchKernelGGL(attn_gru_kernel, dim3(256), dim3(512), 0, stream,
                       x, att_v, att_w, att_u, gk, grk, gbias, out);
}

// Round 9
// 457.771 us; speedup vs baseline: 3.0012x; 2.1639x over previous
//
#include <hip/hip_runtime.h>

// AttentionRNN: B=64, NUM=8, TC=64, H=128. bn=512 sequences.
// R9 = R1 template (validated 607us: 256 thr/block, 2 seqs, launch_bounds(256,1),
// no spill) with ONE change: phase-D weight stream chunked at unroll-16
// (8 chunks x 16 float4 loads, single static-indexed w[16] buffer) for ~16
// outstanding L2 loads instead of ~4, + float4 LDS input reads.

#define OFF_U     0      // [64][64] att_u staging (prologue only)
#define OFF_XMRM  4096   // [mat][seq][384] = [2][2][384]
#define OFF_HST   5632   // [2][128]
#define OFF_HPP   5888   // [2][4][64]  h_part partials
#define OFF_HPART 6400   // [2][64]
#define OFF_XTV   6528   // [2][128]  x_t = a * x_col
#define OFF_VV    6784   // [64] att_v
#define OFF_RED   6848   // [16] softmax cross-wave scratch
#define LDS_FLOATS 6864

#define FMA4(ACC, W, S) do { (ACC).x += (W).x*(S); (ACC).y += (W).y*(S); \
                             (ACC).z += (W).z*(S); (ACC).w += (W).w*(S); } while(0)

__global__ __launch_bounds__(256, 1)
void attn_gru_kernel(const float* __restrict__ x, const float* __restrict__ att_v,
                     const float* __restrict__ att_w, const float* __restrict__ att_u,
                     const float* __restrict__ gk, const float* __restrict__ grk,
                     const float* __restrict__ gbias, float* __restrict__ out) {
    __shared__ float lds[LDS_FLOATS];
    const int tid = threadIdx.x;
    const int bn0 = blockIdx.x * 2;

    // stage U, v; init h = 0
    for (int i = tid; i < 4096; i += 256) lds[OFF_U + i] = att_u[i];
    if (tid < 64) lds[OFF_VV + tid] = att_v[tid];
    lds[OFF_HST + tid] = 0.0f;
    __syncthreads();

    const int seq = tid >> 7;   // 0/1 : which of the block's 2 sequences
    const int hh  = tid & 127;  // feature index
    const int s_  = tid & 63;
    const int hg  = tid >> 6;   // 0..3 (also wave id)

    // per-thread uproj[seq][hh][0..63] in registers
    float upreg[64];
    #pragma unroll
    for (int s2 = 0; s2 < 64; ++s2) upreg[s2] = 0.0f;
    {
        const float* xb = x + (size_t)(bn0 + seq) * 8192 + hh;
        for (int t = 0; t < 64; ++t) {
            float xv = xb[t * 128];                  // coalesced across hh lanes
            const float* Ur = lds + OFF_U + t * 64;  // broadcast reads
            #pragma unroll
            for (int s2 = 0; s2 < 64; ++s2) upreg[s2] += xv * Ur[s2];
        }
    }

    // att_w in registers: thread (hg, s_) owns W[hg*32+k][s_], k=0..31
    float wreg[32];
    #pragma unroll
    for (int k = 0; k < 32; ++k) wreg[k] = att_w[(hg * 32 + k) * 64 + s_];

    // GRU matvec (phase D) per-thread constants: quad of weight columns
    const int col4 = tid * 4;                 // 0..764 for tid<192
    const int dmat = (col4 >= 384) ? 1 : 0;   // 0 -> gru_kernel (x_t), 1 -> gru_rkernel (h)
    const int dj   = col4 - dmat * 384;       // multiple of 4
    const float* Wm = (dmat ? grk : gk) + dj;
    const int ivoff = dmat ? OFF_HST : OFF_XTV;
    float4 dbias = make_float4(0.f, 0.f, 0.f, 0.f);
    if (tid < 192) dbias = *(const float4*)(gbias + dmat * 384 + dj);

    __syncthreads();

    for (int t = 0; t < 64; ++t) {
        // ---- A: h_part partials: h_part[s] = sum_h h[h] * W[h][s]
        {
            float p0 = 0.f, p1 = 0.f;
            #pragma unroll
            for (int k = 0; k < 32; ++k) {
                float w = wreg[k];
                p0 += lds[OFF_HST + hg * 32 + k] * w;        // broadcast
                p1 += lds[OFF_HST + 128 + hg * 32 + k] * w;
            }
            lds[OFF_HPP + (0 * 4 + hg) * 64 + s_] = p0;
            lds[OFF_HPP + (1 * 4 + hg) * 64 + s_] = p1;
        }
        __syncthreads();
        // ---- B: reduce 4 row-group partials
        if (tid < 128) {
            int sq = tid >> 6, ss = tid & 63;
            lds[OFF_HPART + sq * 64 + ss] =
                  lds[OFF_HPP + (sq * 4 + 0) * 64 + ss]
                + lds[OFF_HPP + (sq * 4 + 1) * 64 + ss]
                + lds[OFF_HPP + (sq * 4 + 2) * 64 + ss]
                + lds[OFF_HPP + (sq * 4 + 3) * 64 + ss];
        }
        __syncthreads();
        // ---- C: e[hh] = sum_s tanh(h_part[s] + uproj[hh][s]) * v[s]; softmax over hh
        float e = 0.f;
        {
            const float* hp = lds + OFF_HPART + seq * 64;
            #pragma unroll
            for (int s2 = 0; s2 < 64; ++s2) {
                float arg = hp[s2] + upreg[s2];
                float u2 = __expf(2.0f * arg);                   // tanh = 1 - 2/(e^{2x}+1)
                float th = 1.0f - __fdividef(2.0f, u2 + 1.0f);
                e += th * lds[OFF_VV + s2];
            }
        }
        float m = e;
        #pragma unroll
        for (int off = 32; off >= 1; off >>= 1) m = fmaxf(m, __shfl_xor(m, off, 64));
        if ((tid & 63) == 0) lds[OFF_RED + hg] = m;
        __syncthreads();
        m = fmaxf(lds[OFF_RED + seq * 2], lds[OFF_RED + seq * 2 + 1]);
        float p = __expf(e - m);
        float sm = p;
        #pragma unroll
        for (int off = 32; off >= 1; off >>= 1) sm += __shfl_xor(sm, off, 64);
        if ((tid & 63) == 0) lds[OFF_RED + 8 + hg] = sm;
        __syncthreads();
        float denom = lds[OFF_RED + 8 + seq * 2] + lds[OFF_RED + 8 + seq * 2 + 1];
        float a = __fdividef(p, denom);
        float xv = x[(size_t)(bn0 + seq) * 8192 + t * 128 + hh];
        lds[OFF_XTV + seq * 128 + hh] = a * xv;
        __syncthreads();
        // ---- D: xm = x_t@K + b_in ; rm = h@R + b_rec. 192 threads x 4 adjacent cols.
        //       Chunked unroll-16: 16 float4 weight loads in flight per chunk.
        if (tid < 192) {
            float4 a0 = make_float4(0.f, 0.f, 0.f, 0.f);
            float4 a1 = make_float4(0.f, 0.f, 0.f, 0.f);
            #pragma unroll 1
            for (int c = 0; c < 8; ++c) {
                float4 w[16];
                #pragma unroll
                for (int r = 0; r < 16; ++r)
                    w[r] = *(const float4*)(Wm + (size_t)(c * 16 + r) * 384);
                const float* i0 = lds + ivoff + c * 16;
                float4 iA0 = *(const float4*)(i0);
                float4 iA1 = *(const float4*)(i0 + 4);
                float4 iA2 = *(const float4*)(i0 + 8);
                float4 iA3 = *(const float4*)(i0 + 12);
                float4 iB0 = *(const float4*)(i0 + 128);
                float4 iB1 = *(const float4*)(i0 + 132);
                float4 iB2 = *(const float4*)(i0 + 136);
                float4 iB3 = *(const float4*)(i0 + 140);
                FMA4(a0, w[0],  iA0.x); FMA4(a1, w[0],  iB0.x);
                FMA4(a0, w[1],  iA0.y); FMA4(a1, w[1],  iB0.y);
                FMA4(a0, w[2],  iA0.z); FMA4(a1, w[2],  iB0.z);
                FMA4(a0, w[3],  iA0.w); FMA4(a1, w[3],  iB0.w);
                FMA4(a0, w[4],  iA1.x); FMA4(a1, w[4],  iB1.x);
                FMA4(a0, w[5],  iA1.y); FMA4(a1, w[5],  iB1.y);
                FMA4(a0, w[6],  iA1.z); FMA4(a1, w[6],  iB1.z);
                FMA4(a0, w[7],  iA1.w); FMA4(a1, w[7],  iB1.w);
                FMA4(a0, w[8],  iA2.x); FMA4(a1, w[8],  iB2.x);
                FMA4(a0, w[9],  iA2.y); FMA4(a1, w[9],  iB2.y);
                FMA4(a0, w[10], iA2.z); FMA4(a1, w[10], iB2.z);
                FMA4(a0, w[11], iA2.w); FMA4(a1, w[11], iB2.w);
                FMA4(a0, w[12], iA3.x); FMA4(a1, w[12], iB3.x);
                FMA4(a0, w[13], iA3.y); FMA4(a1, w[13], iB3.y);
                FMA4(a0, w[14], iA3.z); FMA4(a1, w[14], iB3.z);
                FMA4(a0, w[15], iA3.w); FMA4(a1, w[15], iB3.w);
            }
            *(float4*)(lds + OFF_XMRM + (dmat * 2 + 0) * 384 + dj) =
                make_float4(a0.x + dbias.x, a0.y + dbias.y, a0.z + dbias.z, a0.w + dbias.w);
            *(float4*)(lds + OFF_XMRM + (dmat * 2 + 1) * 384 + dj) =
                make_float4(a1.x + dbias.x, a1.y + dbias.y, a1.z + dbias.z, a1.w + dbias.w);
        }
        __syncthreads();
        // ---- E: gates
        {
            const float* xm = lds + OFF_XMRM + (0 * 2 + seq) * 384;
            const float* rm = lds + OFF_XMRM + (1 * 2 + seq) * 384;
            float xz = xm[hh], xr = xm[128 + hh], xh = xm[256 + hh];
            float rz = rm[hh], rr = rm[128 + hh], rh = rm[256 + hh];
            float z = __fdividef(1.0f, 1.0f + __expf(-(xz + rz)));
            float r = __fdividef(1.0f, 1.0f + __expf(-(xr + rr)));
            float hc = xh + r * rh;
            hc = hc > 0.f ? hc : 0.f;
            float hold = lds[OFF_HST + seq * 128 + hh];
            lds[OFF_HST + seq * 128 + hh] = z * hold + (1.0f - z) * hc;
        }
        __syncthreads();
    }

    out[(size_t)(bn0 + seq) * 128 + hh] = lds[OFF_HST + seq * 128 + hh];
}

extern "C" void kernel_launch(void* const* d_in, const int* in_sizes, int n_in,
                              void* d_out, int out_size, void* d_ws, size_t ws_size,
                              hipStream_t stream) {
    (void)in_sizes; (void)n_in; (void)out_size; (void)d_ws; (void)ws_size;
    const float* x      = (const float*)d_in[0];
    const float* att_v  = (const float*)d_in[1];
    const float* att_w  = (const float*)d_in[2];
    const float* att_u  = (const float*)d_in[3];
    const float* gk     = (const float*)d_in[4];
    const float* grk    = (const float*)d_in[5];
    const float* gbias  = (const float*)d_in[6];
    float* out = (float*)d_out;
    hipLaunchKernelGGL(attn_gru_kernel, dim3(256), dim3(256), 0, stream,
                       x, att_v, att_w, att_u, gk, grk, gbias, out);
}